// Round 3
// baseline (108.011 us; speedup 1.0000x reference)
//
#include <hip/hip_runtime.h>
#include <hip/hip_bf16.h>

// Problem constants: B=16, T=8192, M=P=128, N2=128. Chunks: 64 per batch, L=128.
#define LCH 128
#define NCH 64
#define NCHUNKS 1024   // 16*64

typedef __attribute__((ext_vector_type(8))) short short8v;
typedef __attribute__((ext_vector_type(4))) short short4v;
typedef __attribute__((ext_vector_type(4))) float f32x4;

// ws layout: float2 region then bf16 packs
//   ws2[0      .. 16384)  Ldinv[r][n] = Ld^{-(r+1)}   (float2)
//   ws2[16384  .. 32768)  Ldp[r][n]   = Ld^{r+1}      (float2)
//   ws2[32768  .. 163840) E[g][n]                      (float2)
//   ws2[163840 .. 294912) CIN[g][n]                    (float2)
#define W2_LDINV 0
#define W2_LDP   16384
#define W2_E     32768
#define W2_CIN   163840
#define WS_WPACK_BYTE  (589824 * 4)         // 32768 bf16 (64 KB): [ntile16][ks4][lane64][j8]
#define WS_CCPACK_BYTE (589824 * 4 + 65536) // 32768 bf16: [ptile8][ks8][lane64][j8]

__device__ inline unsigned short f2bf(float f) {
    union { __hip_bfloat16 h; unsigned short u; } v;
    v.h = __float2bfloat16(f);
    return v.u;
}
__device__ inline short4v pack4(float a, float b, float c, float d) {
    union { __hip_bfloat162 h2[2]; short4v s4; } pk;
    pk.h2[0] = __float22bfloat162_rn(make_float2(a, b));
    pk.h2[1] = __float22bfloat162_rn(make_float2(c, d));
    return pk.s4;
}

// ---------------- k0a: power tables (f64 exact), float2-interleaved ----------------
__global__ void k0_pows(const float* __restrict__ lp, const float* __restrict__ delta,
                        float2* __restrict__ ws2) {
    const int r = blockIdx.x;          // 0..127
    const int tid = threadIdx.x;       // 0..255
    const int n = tid & 127;
    const double d = (double)delta[0];
    const double lre = -exp((double)lp[n]);
    const double lim = (double)lp[128 + n];
    const double kk = (double)(r + 1) * d;
    if (tid < 128) {                   // Ldinv[r][n] = exp(-Lam*kk)
        const double mag = exp(-lre * kk);
        ws2[W2_LDINV + r * 128 + n] = make_float2((float)(mag * cos(lim * kk)),
                                                  (float)(-mag * sin(lim * kk)));
    } else {                           // Ldp[r][n] = exp(Lam*kk)
        const double mag = exp(lre * kk);
        ws2[W2_LDP + r * 128 + n] = make_float2((float)(mag * cos(lim * kk)),
                                                (float)(mag * sin(lim * kk)));
    }
}

// ---------------- k0b: pack W = Bd^T as B-fragments ----------------
// W[m, n'] : n'<128 -> Re(Bd[n'][m]), else Im(Bd[n'-128][m]).
__global__ void k0_wpack(const float* __restrict__ lp, const float* __restrict__ bp,
                         const float* __restrict__ delta, unsigned short* __restrict__ wpack) {
    const int gid = blockIdx.x * 512 + threadIdx.x;    // 0..32767
    const int j = gid & 7;
    const int lane = (gid >> 3) & 63;
    const int ks = (gid >> 9) & 3;
    const int ntile = gid >> 11;
    const int np = ntile * 16 + (lane & 15);
    const int m = ks * 32 + ((lane >> 4) & 3) * 8 + j;
    const int n = np & 127;
    const double d = (double)delta[0];
    const double lre = -exp((double)lp[n]);
    const double lim = (double)lp[128 + n];
    const double er = exp(lre * d);
    const double ldr = er * cos(lim * d), ldi = er * sin(lim * d);
    const double nr = ldr - 1.0, ni = ldi;
    const double den = lre * lre + lim * lim;
    const double cr = (nr * lre + ni * lim) / den;
    const double ci = (ni * lre - nr * lim) / den;
    const double br = (double)bp[n * 128 + m];
    const double bi = (double)bp[16384 + n * 128 + m];
    const double v = (np < 128) ? (cr * br - ci * bi) : (cr * bi + ci * br);
    wpack[gid] = f2bf((float)v);
}

// ---------------- k0c: pack CC (K=256, re/im interleaved along k) ----------------
__global__ void k0_cpack(const float* __restrict__ cp, unsigned short* __restrict__ ccpack) {
    const int gid = blockIdx.x * 512 + threadIdx.x;    // 0..32767
    const int j = gid & 7;
    const int lane = (gid >> 3) & 63;
    const int ks = (gid >> 9) & 7;
    const int ptile = gid >> 12;
    const int p = ptile * 16 + (lane & 15);
    const int k = ks * 32 + ((lane >> 4) & 3) * 8 + j;
    const int n = k >> 1;
    const float v = ((k & 1) == 0) ? 2.0f * cp[p * 128 + n] : -2.0f * cp[16384 + p * 128 + n];
    ccpack[gid] = f2bf(v);
}

// ---------------- shared device helpers ----------------
// stage u chunk (128t x 128m f32) -> LDS bf16 [t][m], swizzle byte ^= (t&7)<<4
__device__ inline void stage_u(const float* __restrict__ uchunk, unsigned short* lds_u) {
    const float4* uf = (const float4*)uchunk;
    const int tid = threadIdx.x;
#pragma unroll
    for (int it = 0; it < 8; ++it) {
        const int f4 = it * 512 + tid;
        const float4 v = uf[f4];
        const int t = f4 >> 5;
        const int m = (f4 & 31) * 4;
        const int byte = (t * 256 + m * 2) ^ ((t & 7) << 4);
        *(short4v*)((char*)lds_u + byte) = pack4(v.x, v.y, v.z, v.w);
    }
}

// GEMM1: Bu[t, n'] for wave w: cols n' in [16w,16w+16) (re, frag 0) and [128+16w, ...) (im, frag 1)
__device__ inline void gemm1(const unsigned short* lds_u, const unsigned short* wpack,
                             int w, int lane, f32x4 acc[8][2]) {
    const short8v* wp = (const short8v*)wpack;
    const int tl = lane & 15;
    const int gq = (lane >> 4) & 3;
    __builtin_amdgcn_s_setprio(1);
#pragma unroll
    for (int ks = 0; ks < 4; ++ks) {
        const short8v b0 = wp[(w * 4 + ks) * 64 + lane];
        const short8v b1 = wp[((8 + w) * 4 + ks) * 64 + lane];
#pragma unroll
        for (int tt = 0; tt < 8; ++tt) {
            const int t = tt * 16 + tl;
            const int byte = (t * 256 + (ks * 32 + gq * 8) * 2) ^ ((t & 7) << 4);
            const short8v a = *(const short8v*)((const char*)lds_u + byte);
            acc[tt][0] = __builtin_amdgcn_mfma_f32_16x16x32_bf16(a, b0, acc[tt][0], 0, 0, 0);
            acc[tt][1] = __builtin_amdgcn_mfma_f32_16x16x32_bf16(a, b1, acc[tt][1], 0, 0, 0);
        }
    }
    __builtin_amdgcn_s_setprio(0);
}

// ---------------- k1: chunk end-states E (zero-init) ----------------
__global__ __launch_bounds__(512, 4) void k1_end(const float* __restrict__ u,
                                                 float2* __restrict__ ws2,
                                                 const unsigned short* __restrict__ wpack) {
    __shared__ unsigned short lds_u[16384];
    const int tid = threadIdx.x;
    const int lane = tid & 63;
    const int w = tid >> 6;
    const int g = blockIdx.x;
    const int b = g >> 6;
    const int c = g & 63;
    stage_u(u + (size_t)(b * 8192 + c * 128) * 128, lds_u);
    __syncthreads();
    f32x4 acc[8][2];
#pragma unroll
    for (int i = 0; i < 8; ++i) { acc[i][0] = (f32x4)0.f; acc[i][1] = (f32x4)0.f; }
    gemm1(lds_u, wpack, w, lane, acc);
    // E[n] = Ld^128 * sum_r Ldinv[r] (.) Bu[r,n]
    const int tl = lane & 15;
    const int gq = (lane >> 4) & 3;
    const int n = w * 16 + tl;
    float er = 0.f, ei = 0.f;
#pragma unroll
    for (int tt = 0; tt < 8; ++tt) {
#pragma unroll
        for (int reg = 0; reg < 4; ++reg) {
            const int r = tt * 16 + gq * 4 + reg;
            const float2 li = ws2[W2_LDINV + r * 128 + n];
            const float br = acc[tt][0][reg], bi = acc[tt][1][reg];
            er += li.x * br - li.y * bi;
            ei += li.x * bi + li.y * br;
        }
    }
    er += __shfl_xor(er, 16); ei += __shfl_xor(ei, 16);
    er += __shfl_xor(er, 32); ei += __shfl_xor(ei, 32);
    const float2 ld = ws2[W2_LDP + 127 * 128 + n];
    if (lane < 16) {
        ws2[W2_E + g * 128 + n] = make_float2(ld.x * er - ld.y * ei,
                                              ld.x * ei + ld.y * er);
    }
}

// ---------------- k2: chunk-level scan -> carry-in ----------------
__global__ void k2_carry(float2* __restrict__ ws2) {
    const int idx = blockIdx.x * 256 + threadIdx.x;   // 0..2047
    const int b = idx >> 7;
    const int n = idx & 127;
    const float2 l = ws2[W2_LDP + 127 * 128 + n];
    float cr = 0.f, ci = 0.f;
    for (int c = 0; c < NCH; ++c) {
        const int o = (b * NCH + c) * 128 + n;
        ws2[W2_CIN + o] = make_float2(cr, ci);
        const float2 e = ws2[W2_E + o];
        const float nr = fmaf(l.x, cr, fmaf(-l.y, ci, e.x));
        const float ni = fmaf(l.x, ci, fmaf(l.y, cr, e.y));
        cr = nr; ci = ni;
    }
}

// ---------------- k3: GEMM1 -> scale -> tri-cumsum MFMA -> scale+carry -> GEMM3 ----------------
// LDS 64 KB total: u [0,32KB) dies after GEMM1; bus (64KB, wave-private rows) aliases it;
// x (64KB) aliases bus after GEMM2. -> 2 blocks/CU.
__global__ __launch_bounds__(512, 4) void k3_main(const float* __restrict__ u,
                                                  const float2* __restrict__ ws2,
                                                  const unsigned short* __restrict__ wpack,
                                                  const unsigned short* __restrict__ ccpack,
                                                  float* __restrict__ y) {
    __shared__ unsigned short lds[32768];     // 64 KB
    unsigned short* lds_u = lds;
    unsigned short* lds_bus = lds;
    const int tid = threadIdx.x;
    const int lane = tid & 63;
    const int w = tid >> 6;
    const int tl = lane & 15;
    const int gq = (lane >> 4) & 3;
    const int g = blockIdx.x;
    const int b = g >> 6;
    const int c = g & 63;
    const int n = w * 16 + tl;

    stage_u(u + (size_t)(b * 8192 + c * 128) * 128, lds_u);
    __syncthreads();

    // GEMM1
    f32x4 acc[8][2];
#pragma unroll
    for (int i = 0; i < 8; ++i) { acc[i][0] = (f32x4)0.f; acc[i][1] = (f32x4)0.f; }
    gemm1(lds_u, wpack, w, lane, acc);
    __syncthreads();   // u dead; bus may now overwrite it

    // scale by Ldinv, write Bus_T [n'][s] bf16 (re rows 0..127, im rows 128..255)
#pragma unroll
    for (int tt = 0; tt < 8; ++tt) {
        float vr[4], vi[4];
#pragma unroll
        for (int reg = 0; reg < 4; ++reg) {
            const int r = tt * 16 + gq * 4 + reg;
            const float2 li = ws2[W2_LDINV + r * 128 + n];
            const float br = acc[tt][0][reg], bi = acc[tt][1][reg];
            vr[reg] = li.x * br - li.y * bi;
            vi[reg] = li.x * bi + li.y * br;
        }
        const int s0 = tt * 16 + gq * 4;
        const int rowr = w * 16 + tl;
        *(short4v*)((char*)lds_bus + ((rowr * 256 + s0 * 2) ^ ((rowr & 7) << 4))) =
            pack4(vr[0], vr[1], vr[2], vr[3]);
        const int rowi = 128 + w * 16 + tl;
        *(short4v*)((char*)lds_bus + ((rowi * 256 + s0 * 2) ^ ((rowi & 7) << 4))) =
            pack4(vi[0], vi[1], vi[2], vi[3]);
    }

    // GEMM2: z = T_lower_ones x Bus  (wave-private rows; no barrier needed)
    short8v ONES, D0, D1;
#pragma unroll
    for (int j = 0; j < 8; ++j) {
        const int sl = gq * 8 + j;
        ONES[j] = (short)0x3F80;
        D0[j] = (sl <= tl) ? (short)0x3F80 : (short)0;
        D1[j] = (sl <= tl + 16) ? (short)0x3F80 : (short)0;
    }
    f32x4 z[8][2];
#pragma unroll
    for (int i = 0; i < 8; ++i) { z[i][0] = (f32x4)0.f; z[i][1] = (f32x4)0.f; }
#pragma unroll
    for (int ks = 0; ks < 4; ++ks) {
        const int rr = w * 16 + tl;
        const short8v b0 = *(const short8v*)((const char*)lds_bus +
                           ((rr * 256 + (ks * 32 + gq * 8) * 2) ^ ((rr & 7) << 4)));
        const int ri = 128 + w * 16 + tl;
        const short8v b1 = *(const short8v*)((const char*)lds_bus +
                           ((ri * 256 + (ks * 32 + gq * 8) * 2) ^ ((ri & 7) << 4)));
#pragma unroll
        for (int tt = 0; tt < 8; ++tt) {
            if (tt < 2 * ks) continue;                  // zero block
            const short8v a = (tt == 2 * ks) ? D0 : ((tt == 2 * ks + 1) ? D1 : ONES);
            z[tt][0] = __builtin_amdgcn_mfma_f32_16x16x32_bf16(a, b0, z[tt][0], 0, 0, 0);
            z[tt][1] = __builtin_amdgcn_mfma_f32_16x16x32_bf16(a, b1, z[tt][1], 0, 0, 0);
        }
    }
    __syncthreads();   // all waves finished reading their bus rows (x overwrites below)

    // x[t][k''] = Ldp[t] (.) (z + carry), interleaved re/im along k''=2n+parity
    const float2 cin = ws2[W2_CIN + g * 128 + n];
#pragma unroll
    for (int tt = 0; tt < 8; ++tt) {
#pragma unroll
        for (int reg = 0; reg < 4; ++reg) {
            const int r = tt * 16 + gq * 4 + reg;
            const float2 ld = ws2[W2_LDP + r * 128 + n];
            const float zr = z[tt][0][reg] + cin.x;
            const float zi = z[tt][1][reg] + cin.y;
            const float xr = ld.x * zr - ld.y * zi;
            const float xi = ld.x * zi + ld.y * zr;
            union { __hip_bfloat162 h2; unsigned u; } pk;
            pk.h2 = __float22bfloat162_rn(make_float2(xr, xi));
            const int byte = (r * 512 + n * 4) ^ ((r & 7) << 4);
            *(unsigned*)((char*)lds + byte) = pk.u;
        }
    }
    __syncthreads();

    // GEMM3: y[t][p] ; wave w owns p-tile w, all t
    const short8v* cc = (const short8v*)ccpack;
    f32x4 yac[8];
#pragma unroll
    for (int i = 0; i < 8; ++i) yac[i] = (f32x4)0.f;
    __builtin_amdgcn_s_setprio(1);
#pragma unroll
    for (int ks = 0; ks < 8; ++ks) {
        const short8v bfrg = cc[(w * 8 + ks) * 64 + lane];
#pragma unroll
        for (int tt = 0; tt < 8; ++tt) {
            const int t = tt * 16 + tl;
            const int byte = (t * 512 + (ks * 32 + gq * 8) * 2) ^ ((t & 7) << 4);
            const short8v a = *(const short8v*)((const char*)lds + byte);
            yac[tt] = __builtin_amdgcn_mfma_f32_16x16x32_bf16(a, bfrg, yac[tt], 0, 0, 0);
        }
    }
    __builtin_amdgcn_s_setprio(0);
    // store y (f32)
    const int p = w * 16 + tl;
    float* yrow = y + (size_t)(b * 8192 + c * 128) * 128;
#pragma unroll
    for (int tt = 0; tt < 8; ++tt) {
#pragma unroll
        for (int reg = 0; reg < 4; ++reg) {
            const int t = tt * 16 + gq * 4 + reg;
            yrow[t * 128 + p] = yac[tt][reg];
        }
    }
}

extern "C" void kernel_launch(void* const* d_in, const int* in_sizes, int n_in,
                              void* d_out, int out_size, void* d_ws, size_t ws_size,
                              hipStream_t stream) {
    const float* u     = (const float*)d_in[0];
    const float* lp    = (const float*)d_in[1];
    const float* bp    = (const float*)d_in[2];
    const float* cp    = (const float*)d_in[3];
    const float* delta = (const float*)d_in[4];
    float* y  = (float*)d_out;
    float2* ws2 = (float2*)d_ws;
    unsigned short* wpack  = (unsigned short*)((char*)d_ws + WS_WPACK_BYTE);
    unsigned short* ccpack = (unsigned short*)((char*)d_ws + WS_CCPACK_BYTE);

    k0_pows <<<128, 256, 0, stream>>>(lp, delta, ws2);
    k0_wpack<<<64, 512, 0, stream>>>(lp, bp, delta, wpack);
    k0_cpack<<<64, 512, 0, stream>>>(cp, ccpack);
    k1_end  <<<NCHUNKS, 512, 0, stream>>>(u, ws2, wpack);
    k2_carry<<<8, 256, 0, stream>>>(ws2);
    k3_main <<<NCHUNKS, 512, 0, stream>>>(u, ws2, wpack, ccpack, y);
}

// Round 4
// 88.356 us; speedup vs baseline: 1.2225x; 1.2225x over previous
//
#include <hip/hip_runtime.h>
#include <hip/hip_bf16.h>

// Problem constants: B=16, T=8192, M=P=128, N2=128. Chunks: 64 per batch, L=128.
#define LCH 128
#define NCH 64
#define NCHUNKS 1024   // 16*64

typedef __attribute__((ext_vector_type(8))) short short8v;
typedef __attribute__((ext_vector_type(4))) short short4v;
typedef __attribute__((ext_vector_type(4))) float f32x4;

// ws layout: float2 region then bf16 packs
#define W2_LDINV 0          // [128 r][128 n]  Ld^{-(r+1)}   (float2)
#define W2_LDP   16384      // [128 r][128 n]  Ld^{r+1}      (float2)
#define W2_E     32768      // [1024 g][128 n]               (float2)
#define W2_CIN   163840     // [1024 g][128 n]               (float2)
#define WS_WPACK_BYTE  (589824 * 4)         // 32768 bf16 (64 KB): [ntile16][ks4][lane64][j8]
#define WS_CCPACK_BYTE (589824 * 4 + 65536) // 32768 bf16: [ptile8][ks8][lane64][j8]

// bus LDS layout (k-blocked): byte(s, n') = (s>>3)*4096 + n'*16 + (s&7)*2
#define BUS_BYTE(s, np) ((((s) >> 3) * 4096) + ((np) * 16) + (((s) & 7) * 2))

__device__ inline unsigned short f2bf(float f) {
    union { __hip_bfloat16 h; unsigned short u; } v;
    v.h = __float2bfloat16(f);
    return v.u;
}
__device__ inline short4v pack4(float a, float b, float c, float d) {
    union { __hip_bfloat162 h2[2]; short4v s4; } pk;
    pk.h2[0] = __float22bfloat162_rn(make_float2(a, b));
    pk.h2[1] = __float22bfloat162_rn(make_float2(c, d));
    return pk.s4;
}

// ---------------- k0a: power tables (f64 exact), float2-interleaved ----------------
__global__ void k0_pows(const float* __restrict__ lp, const float* __restrict__ delta,
                        float2* __restrict__ ws2) {
    const int r = blockIdx.x;          // 0..127
    const int tid = threadIdx.x;       // 0..255
    const int n = tid & 127;
    const double d = (double)delta[0];
    const double lre = -exp((double)lp[n]);
    const double lim = (double)lp[128 + n];
    const double kk = (double)(r + 1) * d;
    if (tid < 128) {
        const double mag = exp(-lre * kk);
        ws2[W2_LDINV + r * 128 + n] = make_float2((float)(mag * cos(lim * kk)),
                                                  (float)(-mag * sin(lim * kk)));
    } else {
        const double mag = exp(lre * kk);
        ws2[W2_LDP + r * 128 + n] = make_float2((float)(mag * cos(lim * kk)),
                                                (float)(mag * sin(lim * kk)));
    }
}

// ---------------- k0b: pack W = Bd^T as B-fragments ----------------
__global__ void k0_wpack(const float* __restrict__ lp, const float* __restrict__ bp,
                         const float* __restrict__ delta, unsigned short* __restrict__ wpack) {
    const int gid = blockIdx.x * 512 + threadIdx.x;    // 0..32767
    const int j = gid & 7;
    const int lane = (gid >> 3) & 63;
    const int ks = (gid >> 9) & 3;
    const int ntile = gid >> 11;
    const int np = ntile * 16 + (lane & 15);
    const int m = ks * 32 + ((lane >> 4) & 3) * 8 + j;
    const int n = np & 127;
    const double d = (double)delta[0];
    const double lre = -exp((double)lp[n]);
    const double lim = (double)lp[128 + n];
    const double er = exp(lre * d);
    const double ldr = er * cos(lim * d), ldi = er * sin(lim * d);
    const double nr = ldr - 1.0, ni = ldi;
    const double den = lre * lre + lim * lim;
    const double cr = (nr * lre + ni * lim) / den;
    const double ci = (ni * lre - nr * lim) / den;
    const double br = (double)bp[n * 128 + m];
    const double bi = (double)bp[16384 + n * 128 + m];
    const double v = (np < 128) ? (cr * br - ci * bi) : (cr * bi + ci * br);
    wpack[gid] = f2bf((float)v);
}

// ---------------- k0c: pack CC (K=256, re/im interleaved along k) ----------------
__global__ void k0_cpack(const float* __restrict__ cp, unsigned short* __restrict__ ccpack) {
    const int gid = blockIdx.x * 512 + threadIdx.x;    // 0..32767
    const int j = gid & 7;
    const int lane = (gid >> 3) & 63;
    const int ks = (gid >> 9) & 7;
    const int ptile = gid >> 12;
    const int p = ptile * 16 + (lane & 15);
    const int k = ks * 32 + ((lane >> 4) & 3) * 8 + j;
    const int n = k >> 1;
    const float v = ((k & 1) == 0) ? 2.0f * cp[p * 128 + n] : -2.0f * cp[16384 + p * 128 + n];
    ccpack[gid] = f2bf(v);
}

// ---------------- shared helper: stage u chunk -> LDS bf16 [t][m], XOR swizzle ----------------
__device__ inline void stage_u(const float* __restrict__ uchunk, unsigned short* lds_u) {
    const float4* uf = (const float4*)uchunk;
    const int tid = threadIdx.x;
#pragma unroll
    for (int it = 0; it < 8; ++it) {
        const int f4 = it * 512 + tid;
        const float4 v = uf[f4];
        const int t = f4 >> 5;
        const int m = (f4 & 31) * 4;
        const int byte = (t * 256 + m * 2) ^ ((t & 7) << 4);
        *(short4v*)((char*)lds_u + byte) = pack4(v.x, v.y, v.z, v.w);
    }
}

// ---------------- k1: chunk end-states E (zero-init), half-split GEMM1 ----------------
__global__ __launch_bounds__(512, 4) void k1_end(const float* __restrict__ u,
                                                 float2* __restrict__ ws2,
                                                 const unsigned short* __restrict__ wpack) {
    __shared__ unsigned short lds_u[16384];   // 32 KB
    const int tid = threadIdx.x;
    const int lane = tid & 63;
    const int w = tid >> 6;
    const int tl = lane & 15;
    const int gq = (lane >> 4) & 3;
    const int g = blockIdx.x;
    const int b = g >> 6;
    const int c = g & 63;
    const int n = w * 16 + tl;
    stage_u(u + (size_t)(b * 8192 + c * 128) * 128, lds_u);
    __syncthreads();
    const short8v* wp = (const short8v*)wpack;
    float er = 0.f, ei = 0.f;
#pragma unroll
    for (int h = 0; h < 2; ++h) {
        f32x4 acc[4][2];
#pragma unroll
        for (int i = 0; i < 4; ++i) { acc[i][0] = (f32x4)0.f; acc[i][1] = (f32x4)0.f; }
        __builtin_amdgcn_s_setprio(1);
#pragma unroll
        for (int ks = 0; ks < 4; ++ks) {
            const short8v b0 = wp[(w * 4 + ks) * 64 + lane];
            const short8v b1 = wp[((8 + w) * 4 + ks) * 64 + lane];
#pragma unroll
            for (int tt2 = 0; tt2 < 4; ++tt2) {
                const int t = (h * 4 + tt2) * 16 + tl;
                const int byte = (t * 256 + (ks * 32 + gq * 8) * 2) ^ ((t & 7) << 4);
                const short8v a = *(const short8v*)((const char*)lds_u + byte);
                acc[tt2][0] = __builtin_amdgcn_mfma_f32_16x16x32_bf16(a, b0, acc[tt2][0], 0, 0, 0);
                acc[tt2][1] = __builtin_amdgcn_mfma_f32_16x16x32_bf16(a, b1, acc[tt2][1], 0, 0, 0);
            }
        }
        __builtin_amdgcn_s_setprio(0);
        __builtin_amdgcn_sched_barrier(0);
#pragma unroll
        for (int tt2 = 0; tt2 < 4; ++tt2) {
#pragma unroll
            for (int reg = 0; reg < 4; ++reg) {
                const int r = (h * 4 + tt2) * 16 + gq * 4 + reg;
                const float2 li = ws2[W2_LDINV + r * 128 + n];
                const float br = acc[tt2][0][reg], bi = acc[tt2][1][reg];
                er += li.x * br - li.y * bi;
                ei += li.x * bi + li.y * br;
            }
        }
        __builtin_amdgcn_sched_barrier(0);
    }
    er += __shfl_xor(er, 16); ei += __shfl_xor(ei, 16);
    er += __shfl_xor(er, 32); ei += __shfl_xor(ei, 32);
    const float2 ld = ws2[W2_LDP + 127 * 128 + n];
    if (lane < 16) {
        ws2[W2_E + g * 128 + n] = make_float2(ld.x * er - ld.y * ei,
                                              ld.x * ei + ld.y * er);
    }
}

// ---------------- k2: chunk-level scan -> carry-in ----------------
__global__ void k2_carry(float2* __restrict__ ws2) {
    const int idx = blockIdx.x * 256 + threadIdx.x;   // 0..2047
    const int b = idx >> 7;
    const int n = idx & 127;
    const float2 l = ws2[W2_LDP + 127 * 128 + n];
    float cr = 0.f, ci = 0.f;
    for (int c = 0; c < NCH; ++c) {
        const int o = (b * NCH + c) * 128 + n;
        ws2[W2_CIN + o] = make_float2(cr, ci);
        const float2 e = ws2[W2_E + o];
        const float nr = fmaf(l.x, cr, fmaf(-l.y, ci, e.x));
        const float ni = fmaf(l.x, ci, fmaf(l.y, cr, e.y));
        cr = nr; ci = ni;
    }
}

// ---------------- k3: GEMM1(2 halves) -> bus -> tri-cumsum MFMA -> x -> GEMM3 ----------------
// LDS 64 KB. u occupies [0,32K). bus is k-blocked: s>=64 half -> [32K,64K) (no u alias),
// s<64 half -> [0,32K) written after the barrier that retires u. x (row-major, XOR
// swizzle) overwrites everything after GEMM2. Peak regs ~110 -> no spill at (512,4).
__global__ __launch_bounds__(512, 4) void k3_main(const float* __restrict__ u,
                                                  const float2* __restrict__ ws2,
                                                  const unsigned short* __restrict__ wpack,
                                                  const unsigned short* __restrict__ ccpack,
                                                  float* __restrict__ y) {
    __shared__ unsigned short lds[32768];     // 64 KB
    unsigned short* lds_u = lds;
    const int tid = threadIdx.x;
    const int lane = tid & 63;
    const int w = tid >> 6;
    const int tl = lane & 15;
    const int gq = (lane >> 4) & 3;
    const int g = blockIdx.x;
    const int b = g >> 6;
    const int c = g & 63;
    const int n = w * 16 + tl;

    stage_u(u + (size_t)(b * 8192 + c * 128) * 128, lds_u);
    __syncthreads();

    const short8v* wp = (const short8v*)wpack;
    // GEMM1 + Ldinv scale + bus write, two halves: h=1 (s>=64) first, then h=0.
#pragma unroll
    for (int hh = 0; hh < 2; ++hh) {
        const int h = 1 - hh;
        f32x4 acc[4][2];
#pragma unroll
        for (int i = 0; i < 4; ++i) { acc[i][0] = (f32x4)0.f; acc[i][1] = (f32x4)0.f; }
        __builtin_amdgcn_s_setprio(1);
#pragma unroll
        for (int ks = 0; ks < 4; ++ks) {
            const short8v b0 = wp[(w * 4 + ks) * 64 + lane];
            const short8v b1 = wp[((8 + w) * 4 + ks) * 64 + lane];
#pragma unroll
            for (int tt2 = 0; tt2 < 4; ++tt2) {
                const int t = (h * 4 + tt2) * 16 + tl;
                const int byte = (t * 256 + (ks * 32 + gq * 8) * 2) ^ ((t & 7) << 4);
                const short8v a = *(const short8v*)((const char*)lds_u + byte);
                acc[tt2][0] = __builtin_amdgcn_mfma_f32_16x16x32_bf16(a, b0, acc[tt2][0], 0, 0, 0);
                acc[tt2][1] = __builtin_amdgcn_mfma_f32_16x16x32_bf16(a, b1, acc[tt2][1], 0, 0, 0);
            }
        }
        __builtin_amdgcn_s_setprio(0);
        __builtin_amdgcn_sched_barrier(0);
        if (h == 0) __syncthreads();   // all waves done reading u; s<64 bus may overwrite it
#pragma unroll
        for (int tt2 = 0; tt2 < 4; ++tt2) {
            float vr[4], vi[4];
#pragma unroll
            for (int reg = 0; reg < 4; ++reg) {
                const int r = (h * 4 + tt2) * 16 + gq * 4 + reg;
                const float2 li = ws2[W2_LDINV + r * 128 + n];
                const float br = acc[tt2][0][reg], bi = acc[tt2][1][reg];
                vr[reg] = li.x * br - li.y * bi;
                vi[reg] = li.x * bi + li.y * br;
            }
            const int s0 = (h * 4 + tt2) * 16 + gq * 4;
            const int rowr = w * 16 + tl;
            const int rowi = 128 + rowr;
            *(short4v*)((char*)lds + BUS_BYTE(s0, rowr)) = pack4(vr[0], vr[1], vr[2], vr[3]);
            *(short4v*)((char*)lds + BUS_BYTE(s0, rowi)) = pack4(vi[0], vi[1], vi[2], vi[3]);
        }
        __builtin_amdgcn_sched_barrier(0);
    }

    // GEMM2: z = T_lower_ones x Bus  (wave-private rows; no barrier needed)
    short8v ONES, D0, D1;
#pragma unroll
    for (int j = 0; j < 8; ++j) {
        const int sl = gq * 8 + j;
        ONES[j] = (short)0x3F80;
        D0[j] = (sl <= tl) ? (short)0x3F80 : (short)0;
        D1[j] = (sl <= tl + 16) ? (short)0x3F80 : (short)0;
    }
    f32x4 z[8][2];
#pragma unroll
    for (int i = 0; i < 8; ++i) { z[i][0] = (f32x4)0.f; z[i][1] = (f32x4)0.f; }
#pragma unroll
    for (int ks = 0; ks < 4; ++ks) {
        const int sb = ks * 32 + gq * 8;                 // frag k-base, (sb&7)==0
        const int rowr = w * 16 + tl;
        const int rowi = 128 + rowr;
        const short8v b0 = *(const short8v*)((const char*)lds + BUS_BYTE(sb, rowr));
        const short8v b1 = *(const short8v*)((const char*)lds + BUS_BYTE(sb, rowi));
#pragma unroll
        for (int tt = 0; tt < 8; ++tt) {
            if (tt < 2 * ks) continue;                   // zero block
            const short8v a = (tt == 2 * ks) ? D0 : ((tt == 2 * ks + 1) ? D1 : ONES);
            z[tt][0] = __builtin_amdgcn_mfma_f32_16x16x32_bf16(a, b0, z[tt][0], 0, 0, 0);
            z[tt][1] = __builtin_amdgcn_mfma_f32_16x16x32_bf16(a, b1, z[tt][1], 0, 0, 0);
        }
    }
    __syncthreads();   // all waves finished reading their bus rows (x overwrites below)

    // x[t][k''] = Ldp[t] (.) (z + carry), interleaved re/im along k''=2n+parity
    const float2 cin = ws2[W2_CIN + g * 128 + n];
#pragma unroll
    for (int tt = 0; tt < 8; ++tt) {
#pragma unroll
        for (int reg = 0; reg < 4; ++reg) {
            const int r = tt * 16 + gq * 4 + reg;
            const float2 ld = ws2[W2_LDP + r * 128 + n];
            const float zr = z[tt][0][reg] + cin.x;
            const float zi = z[tt][1][reg] + cin.y;
            const float xr = ld.x * zr - ld.y * zi;
            const float xi = ld.x * zi + ld.y * zr;
            union { __hip_bfloat162 h2; unsigned uu; } pk;
            pk.h2 = __float22bfloat162_rn(make_float2(xr, xi));
            const int byte = (r * 512 + n * 4) ^ ((r & 7) << 4);
            *(unsigned*)((char*)lds + byte) = pk.uu;
        }
    }
    __syncthreads();

    // GEMM3: y[t][p] ; wave w owns p-tile w, all t
    const short8v* cc = (const short8v*)ccpack;
    f32x4 yac[8];
#pragma unroll
    for (int i = 0; i < 8; ++i) yac[i] = (f32x4)0.f;
    __builtin_amdgcn_s_setprio(1);
#pragma unroll
    for (int ks = 0; ks < 8; ++ks) {
        const short8v bfrg = cc[(w * 8 + ks) * 64 + lane];
#pragma unroll
        for (int tt = 0; tt < 8; ++tt) {
            const int t = tt * 16 + tl;
            const int byte = (t * 512 + (ks * 32 + gq * 8) * 2) ^ ((t & 7) << 4);
            const short8v a = *(const short8v*)((const char*)lds + byte);
            yac[tt] = __builtin_amdgcn_mfma_f32_16x16x32_bf16(a, bfrg, yac[tt], 0, 0, 0);
        }
    }
    __builtin_amdgcn_s_setprio(0);
    // store y (f32)
    const int p = w * 16 + tl;
    float* yrow = y + (size_t)(b * 8192 + c * 128) * 128;
#pragma unroll
    for (int tt = 0; tt < 8; ++tt) {
#pragma unroll
        for (int reg = 0; reg < 4; ++reg) {
            const int t = tt * 16 + gq * 4 + reg;
            yrow[t * 128 + p] = yac[tt][reg];
        }
    }
}

extern "C" void kernel_launch(void* const* d_in, const int* in_sizes, int n_in,
                              void* d_out, int out_size, void* d_ws, size_t ws_size,
                              hipStream_t stream) {
    const float* u     = (const float*)d_in[0];
    const float* lp    = (const float*)d_in[1];
    const float* bp    = (const float*)d_in[2];
    const float* cp    = (const float*)d_in[3];
    const float* delta = (const float*)d_in[4];
    float* y  = (float*)d_out;
    float2* ws2 = (float2*)d_ws;
    unsigned short* wpack  = (unsigned short*)((char*)d_ws + WS_WPACK_BYTE);
    unsigned short* ccpack = (unsigned short*)((char*)d_ws + WS_CCPACK_BYTE);

    k0_pows <<<128, 256, 0, stream>>>(lp, delta, ws2);
    k0_wpack<<<64, 512, 0, stream>>>(lp, bp, delta, wpack);
    k0_cpack<<<64, 512, 0, stream>>>(cp, ccpack);
    k1_end  <<<NCHUNKS, 512, 0, stream>>>(u, ws2, wpack);
    k2_carry<<<8, 256, 0, stream>>>(ws2);
    k3_main <<<NCHUNKS, 512, 0, stream>>>(u, ws2, wpack, ccpack, y);
}